// Round 6
// baseline (284.026 us; speedup 1.0000x reference)
//
#include <hip/hip_runtime.h>

#define B_ 4
#define T_ 4096
#define D_ 2048
#define R_ 512
#define NPAIR (T_ - 1)
#define EPS_ 1e-12f

// ---------------- Kernel 1: fused norms + adjacent cosine similarity ----------------
__global__ __launch_bounds__(256) void adj_fused_k(const float* __restrict__ x,
                                                   float* __restrict__ adj) {
    const int i = blockIdx.x;  // 0..NPAIR-1
    const float4* r0 = (const float4*)(x + (size_t)i * D_);
    const float4* r1 = (const float4*)(x + (size_t)(i + 1) * D_);
    float4 a0 = r0[threadIdx.x], a1 = r0[threadIdx.x + 256];
    float4 b0 = r1[threadIdx.x], b1 = r1[threadIdx.x + 256];

    float sa = a0.x * a0.x + a0.y * a0.y + a0.z * a0.z + a0.w * a0.w +
               a1.x * a1.x + a1.y * a1.y + a1.z * a1.z + a1.w * a1.w;
    float sb = b0.x * b0.x + b0.y * b0.y + b0.z * b0.z + b0.w * b0.w +
               b1.x * b1.x + b1.y * b1.y + b1.z * b1.z + b1.w * b1.w;
    #pragma unroll
    for (int off = 1; off < 64; off <<= 1) {
        sa += __shfl_xor(sa, off, 64);
        sb += __shfl_xor(sb, off, 64);
    }
    __shared__ float wsa[4], wsb[4], wss[4];
    const int w = threadIdx.x >> 6;
    if ((threadIdx.x & 63) == 0) { wsa[w] = sa; wsb[w] = sb; }
    __syncthreads();
    const float ni = fmaxf(sqrtf(wsa[0] + wsa[1] + wsa[2] + wsa[3]), EPS_);
    const float nj = fmaxf(sqrtf(wsb[0] + wsb[1] + wsb[2] + wsb[3]), EPS_);

    float s = (a0.x / ni) * (b0.x / nj) + (a0.y / ni) * (b0.y / nj) +
              (a0.z / ni) * (b0.z / nj) + (a0.w / ni) * (b0.w / nj) +
              (a1.x / ni) * (b1.x / nj) + (a1.y / ni) * (b1.y / nj) +
              (a1.z / ni) * (b1.z / nj) + (a1.w / ni) * (b1.w / nj);
    #pragma unroll
    for (int off = 1; off < 64; off <<= 1) s += __shfl_xor(s, off, 64);
    if ((threadIdx.x & 63) == 0) wss[w] = s;
    __syncthreads();
    if (threadIdx.x == 0) adj[i] = wss[0] + wss[1] + wss[2] + wss[3];
}

// ---------------- Kernel 2: locally-dominant matching + radix top-512 ----------------
// 256 threads (4 waves) to make barriers cheap; 2 barriers per matching round.
// Phase A: parallel locally-dominant matching == uncapped greedy matching S.
//   Terminates: the live element with globally max key is always accepted.
// Phase B: capped greedy == 512 largest-key members of S (acceptances occur in
//   descending key order until the cap); exact threshold via byte-radix descent
//   (keys unique: index embedded in low bits).
__global__ __launch_bounds__(256) void select_k(const float* __restrict__ adj,
                                                int* __restrict__ m_out) {
    __shared__ unsigned long long ka[T_];
    __shared__ unsigned char state[T_];  // 0=live 1=accepted 2=dead
    __shared__ unsigned char dec[T_];
    __shared__ int hist[256];
    __shared__ int sflag;
    __shared__ int sneed;
    __shared__ unsigned long long thrsh;
    const int tid = threadIdx.x;

    for (int i = tid; i < T_; i += 256) {
        if (i < NPAIR) {
            unsigned u = __float_as_uint(adj[i]);
            u ^= (u & 0x80000000u) ? 0xFFFFFFFFu : 0x80000000u;  // orderable asc
            ka[i] = ((unsigned long long)u << 32) | (unsigned)(NPAIR - 1 - i);
            state[i] = 0;
        } else {
            ka[i] = 0ull;
            state[i] = 2;
        }
    }
    __syncthreads();

    // ---- Phase A ----
    for (;;) {
        if (tid == 0) sflag = 0;
        for (int i = tid; i < NPAIR; i += 256) {
            bool acc = false;
            if (state[i] == 0) {
                unsigned long long k = ka[i];
                bool okl = (i == 0)         || state[i - 1] != 0 || k > ka[i - 1];
                bool okr = (i == NPAIR - 1) || state[i + 1] != 0 || k > ka[i + 1];
                acc = okl && okr;
            }
            dec[i] = acc ? 1 : 0;
        }
        __syncthreads();  // dec[] + sflag reset visible
        bool anyLive = false;
        for (int i = tid; i < NPAIR; i += 256) {
            unsigned char st = state[i];
            if (st == 0) {
                if (dec[i]) st = 1;
                else if ((i > 0 && dec[i - 1]) || (i < NPAIR - 1 && dec[i + 1])) st = 2;
                state[i] = st;
                anyLive |= (st == 0);
            }
        }
        if (anyLive) sflag = 1;  // racy same-value store: fine
        __syncthreads();         // state[] + sflag visible
        if (sflag == 0) break;
    }

    // ---- Phase B: exact 512th-largest key among accepted ----
    if (tid == 0) { thrsh = 0ull; sneed = R_; }
    for (int byte = 7; byte >= 0; --byte) {
        hist[tid] = 0;
        __syncthreads();
        const int shift = byte * 8;
        for (int i = tid; i < NPAIR; i += 256) {
            if (state[i] == 1) {
                unsigned long long k = ka[i];
                bool match = (byte == 7) || ((k >> (shift + 8)) == (thrsh >> (shift + 8)));
                if (match) atomicAdd(&hist[(int)((k >> shift) & 0xFF)], 1);
            }
        }
        __syncthreads();
        if (tid < 64) {
            const int l = tid;
            int c0 = hist[4 * l], c1 = hist[4 * l + 1], c2 = hist[4 * l + 2], c3 = hist[4 * l + 3];
            int g = c0 + c1 + c2 + c3;
            int G = g;  // inclusive suffix-sum over 64 lane groups
            #pragma unroll
            for (int off = 1; off < 64; off <<= 1) {
                int o = __shfl_down(G, off, 64);
                G += (l + off < 64) ? o : 0;
            }
            const int aboveGroup = G - g;
            const int need = sneed;
            int ca3 = aboveGroup;
            int ca2 = ca3 + c3;
            int ca1 = ca2 + c2;
            int ca0 = ca1 + c1;
            int selv = -1, selca = 0;
            if      (ca3 < need && need <= ca3 + c3) { selv = 4 * l + 3; selca = ca3; }
            else if (ca2 < need && need <= ca2 + c2) { selv = 4 * l + 2; selca = ca2; }
            else if (ca1 < need && need <= ca1 + c1) { selv = 4 * l + 1; selca = ca1; }
            else if (ca0 < need && need <= ca0 + c0) { selv = 4 * l + 0; selca = ca0; }
            if (selv >= 0) {  // exactly one lane-bin matches globally
                thrsh |= ((unsigned long long)(unsigned)selv) << shift;
                sneed = need - selca;
            }
        }
        __syncthreads();
    }

    // ---- direct marking: 1 = starts selected pair, 2 = ends selected pair ----
    const unsigned long long thr = thrsh;
    for (int i = tid; i < T_; i += 256) {
        int mv = 0;
        if (i < NPAIR && state[i] == 1 && ka[i] >= thr) mv = 1;
        else if (i > 0 && state[i - 1] == 1 && ka[i - 1] >= thr) mv = 2;
        m_out[i] = mv;
    }
}

// ---------------- Kernel 3: pointwise merge sweep ----------------
__global__ __launch_bounds__(256) void apply_merge_k(const float* __restrict__ x,
                                                     const int* __restrict__ m,
                                                     float* __restrict__ out) {
    const int D4 = D_ / 4;          // 512 float4 per row
    const int total = B_ * T_ * D4; // 8388608
    const float4* xv = (const float4*)x;
    float4* ov = (float4*)out;
    for (int idx = blockIdx.x * 256 + threadIdx.x; idx < total;
         idx += gridDim.x * 256) {
        int row = idx >> 9;
        int t = row & (T_ - 1);
        int mm = m[t];
        float4 v = xv[idx];
        if (mm) {
            int off = (mm == 1) ? D4 : -D4;
            float4 w = xv[idx + off];
            v.x = 0.5f * (v.x + w.x);
            v.y = 0.5f * (v.y + w.y);
            v.z = 0.5f * (v.z + w.z);
            v.w = 0.5f * (v.w + w.w);
        }
        ov[idx] = v;
    }
}

extern "C" void kernel_launch(void* const* d_in, const int* in_sizes, int n_in,
                              void* d_out, int out_size, void* d_ws, size_t ws_size,
                              hipStream_t stream) {
    const float* x = (const float*)d_in[0];
    float* out = (float*)d_out;
    float* adj = (float*)d_ws;      // 4096 floats
    int* m = (int*)(adj + T_);      // 4096 ints

    adj_fused_k<<<NPAIR, 256, 0, stream>>>(x, adj);
    select_k<<<1, 256, 0, stream>>>(adj, m);
    apply_merge_k<<<8192, 256, 0, stream>>>(x, m, out);
}

// Round 8
// 269.056 us; speedup vs baseline: 1.0556x; 1.0556x over previous
//
#include <hip/hip_runtime.h>

#define B_ 4
#define T_ 4096
#define D_ 2048
#define R_ 512
#define NPAIR (T_ - 1)
#define EPS_ 1e-12f
typedef unsigned long long ull;

// ---------------- Kernel 1: fused norms + adjacent cosine similarity ----------------
__global__ __launch_bounds__(256) void adj_fused_k(const float* __restrict__ x,
                                                   float* __restrict__ adj) {
    const int i = blockIdx.x;  // 0..NPAIR-1
    const float4* r0 = (const float4*)(x + (size_t)i * D_);
    const float4* r1 = (const float4*)(x + (size_t)(i + 1) * D_);
    float4 a0 = r0[threadIdx.x], a1 = r0[threadIdx.x + 256];
    float4 b0 = r1[threadIdx.x], b1 = r1[threadIdx.x + 256];

    float sa = a0.x * a0.x + a0.y * a0.y + a0.z * a0.z + a0.w * a0.w +
               a1.x * a1.x + a1.y * a1.y + a1.z * a1.z + a1.w * a1.w;
    float sb = b0.x * b0.x + b0.y * b0.y + b0.z * b0.z + b0.w * b0.w +
               b1.x * b1.x + b1.y * b1.y + b1.z * b1.z + b1.w * b1.w;
    #pragma unroll
    for (int off = 1; off < 64; off <<= 1) {
        sa += __shfl_xor(sa, off, 64);
        sb += __shfl_xor(sb, off, 64);
    }
    __shared__ float wsa[4], wsb[4], wss[4];
    const int w = threadIdx.x >> 6;
    if ((threadIdx.x & 63) == 0) { wsa[w] = sa; wsb[w] = sb; }
    __syncthreads();
    const float ni = fmaxf(sqrtf(wsa[0] + wsa[1] + wsa[2] + wsa[3]), EPS_);
    const float nj = fmaxf(sqrtf(wsb[0] + wsb[1] + wsb[2] + wsb[3]), EPS_);

    float s = (a0.x / ni) * (b0.x / nj) + (a0.y / ni) * (b0.y / nj) +
              (a0.z / ni) * (b0.z / nj) + (a0.w / ni) * (b0.w / nj) +
              (a1.x / ni) * (b1.x / nj) + (a1.y / ni) * (b1.y / nj) +
              (a1.z / ni) * (b1.z / nj) + (a1.w / ni) * (b1.w / nj);
    #pragma unroll
    for (int off = 1; off < 64; off <<= 1) s += __shfl_xor(s, off, 64);
    if ((threadIdx.x & 63) == 0) wss[w] = s;
    __syncthreads();
    if (threadIdx.x == 0) adj[i] = wss[0] + wss[1] + wss[2] + wss[3];
}

// ---------------- Kernel 2: bitmask locally-dominant matching + radix top-512 ----------------
// Phase A (wave 0 only, zero barriers): comparisons GL[i]=k[i]>k[i-1],
// GR[i]=k[i]>k[i+1] are STATIC -> matching rounds are pure 64-bit mask algebra.
// Lane l holds elements [64l, 64l+64) as bits of {live, acc} registers.
// Phase B: capped greedy == 512 largest-key accepted pairs; exact threshold
// via byte-radix descent (keys unique: index in low bits). Twice verified.
__global__ __launch_bounds__(256) void select_k(const float* __restrict__ adj,
                                                int* __restrict__ m_out) {
    __shared__ ull ka[T_];
    __shared__ ull accM[64];
    __shared__ int hist[256];
    __shared__ int sneed;
    __shared__ ull thrsh;
    const int tid = threadIdx.x;

    for (int i = tid; i < T_; i += 256) {
        if (i < NPAIR) {
            unsigned u = __float_as_uint(adj[i]);
            u ^= (u & 0x80000000u) ? 0xFFFFFFFFu : 0x80000000u;  // orderable asc
            ka[i] = ((ull)u << 32) | (unsigned)(NPAIR - 1 - i);  // big = earlier greedy
        } else {
            ka[i] = 0ull;  // padding slot 4095
        }
    }
    if (tid == 0) { thrsh = 0ull; sneed = R_; }
    __syncthreads();

    // ---- Phase A: wave-synchronous bitmask matching ----
    if (tid < 64) {
        const int lane = tid;
        // Pack static comparison masks: bit b of lane l = element 64l+b.
        ull GL = 0, GR = 0;
        for (int g = 0; g < 64; ++g) {
            const int i = g * 64 + lane;
            const ull k = ka[i];
            bool gl = (i == 0) || (k > ka[i - 1]);
            bool gr = (i >= NPAIR - 1) || (k > ka[i + 1]);
            ull bgl = __ballot(gl);
            ull bgr = __ballot(gr);
            if (lane == g) { GL = bgl; GR = bgr; }
        }
        ull live = ~0ull;
        if (lane == 63) live &= ~(1ull << 63);  // slot 4095 = padding, never live
        ull acc = 0;
        for (;;) {
            ull upl = __shfl_up(live, 1, 64);
            ull dnl = __shfl_down(live, 1, 64);
            ull liveL = (live << 1) | ((lane == 0) ? 0ull : (upl >> 63));
            ull liveR = (live >> 1) | ((lane == 63) ? 0ull : (dnl << 63));
            ull a = live & (~liveL | GL) & (~liveR | GR);  // locally dominant
            ull upa = __shfl_up(a, 1, 64);
            ull dna = __shfl_down(a, 1, 64);
            ull aL = (a << 1) | ((lane == 0) ? 0ull : (upa >> 63));
            ull aR = (a >> 1) | ((lane == 63) ? 0ull : (dna << 63));
            acc |= a;
            live &= ~(a | aL | aR);  // accepted + killed neighbors leave
            if (__ballot(live != 0ull) == 0ull) break;
        }
        accM[lane] = acc;
    }
    __syncthreads();

    // ---- Phase B: exact 512th-largest key among accepted ----
    for (int byte = 7; byte >= 0; --byte) {
        const ull tcur = thrsh;  // stable since last round's trailing barrier
        hist[tid] = 0;
        __syncthreads();
        const int shift = byte * 8;
        for (int i = tid; i < NPAIR; i += 256) {
            if ((accM[i >> 6] >> (i & 63)) & 1ull) {
                const ull k = ka[i];
                bool match = (byte == 7) || ((k >> (shift + 8)) == (tcur >> (shift + 8)));
                if (match) atomicAdd(&hist[(int)((k >> shift) & 0xFF)], 1);
            }
        }
        __syncthreads();
        if (tid < 64) {
            const int l = tid;
            int c0 = hist[4 * l], c1 = hist[4 * l + 1], c2 = hist[4 * l + 2], c3 = hist[4 * l + 3];
            int g = c0 + c1 + c2 + c3;
            int G = g;  // inclusive suffix-sum over 64 lane groups
            #pragma unroll
            for (int off = 1; off < 64; off <<= 1) {
                int o = __shfl_down(G, off, 64);
                G += (l + off < 64) ? o : 0;
            }
            const int aboveGroup = G - g;
            const int need = sneed;
            int ca3 = aboveGroup;
            int ca2 = ca3 + c3;
            int ca1 = ca2 + c2;
            int ca0 = ca1 + c1;
            int selv = -1, selca = 0;
            if      (ca3 < need && need <= ca3 + c3) { selv = 4 * l + 3; selca = ca3; }
            else if (ca2 < need && need <= ca2 + c2) { selv = 4 * l + 2; selca = ca2; }
            else if (ca1 < need && need <= ca1 + c1) { selv = 4 * l + 1; selca = ca1; }
            else if (ca0 < need && need <= ca0 + c0) { selv = 4 * l + 0; selca = ca0; }
            if (selv >= 0) {  // exactly one lane-bin matches globally
                thrsh |= ((ull)(unsigned)selv) << shift;
                sneed = need - selca;
            }
        }
        __syncthreads();
    }

    // ---- direct marking: 1 = starts selected pair, 2 = ends selected pair ----
    const ull thr = thrsh;
    for (int i = tid; i < T_; i += 256) {
        int mv = 0;
        bool self = (i < NPAIR) && ((accM[i >> 6] >> (i & 63)) & 1ull) && ka[i] >= thr;
        bool left = (i > 0) && ((accM[(i - 1) >> 6] >> ((i - 1) & 63)) & 1ull) && ka[i - 1] >= thr;
        if (self) mv = 1;
        else if (left) mv = 2;  // disjoint with self: pairs non-overlapping
        m_out[i] = mv;
    }
}

// ---------------- Kernel 3: pointwise merge sweep ----------------
__global__ __launch_bounds__(256) void apply_merge_k(const float* __restrict__ x,
                                                     const int* __restrict__ m,
                                                     float* __restrict__ out) {
    const int D4 = D_ / 4;          // 512 float4 per row
    const int total = B_ * T_ * D4; // 8388608
    const float4* xv = (const float4*)x;
    float4* ov = (float4*)out;
    for (int idx = blockIdx.x * 256 + threadIdx.x; idx < total;
         idx += gridDim.x * 256) {
        int row = idx >> 9;
        int t = row & (T_ - 1);
        int mm = m[t];
        float4 v = xv[idx];
        if (mm) {
            int off = (mm == 1) ? D4 : -D4;
            float4 w = xv[idx + off];
            v.x = 0.5f * (v.x + w.x);
            v.y = 0.5f * (v.y + w.y);
            v.z = 0.5f * (v.z + w.z);
            v.w = 0.5f * (v.w + w.w);
        }
        ov[idx] = v;
    }
}

extern "C" void kernel_launch(void* const* d_in, const int* in_sizes, int n_in,
                              void* d_out, int out_size, void* d_ws, size_t ws_size,
                              hipStream_t stream) {
    const float* x = (const float*)d_in[0];
    float* out = (float*)d_out;
    float* adj = (float*)d_ws;      // 4096 floats
    int* m = (int*)(adj + T_);      // 4096 ints

    adj_fused_k<<<NPAIR, 256, 0, stream>>>(x, adj);
    select_k<<<1, 256, 0, stream>>>(adj, m);
    apply_merge_k<<<8192, 256, 0, stream>>>(x, m, out);
}